// Round 5
// baseline (20.038 us; speedup 1.0000x reference)
//
#include <hip/hip_runtime.h>
#include <math.h>

// Problem constants: B=2, N=1024, H=128, E=32
#define NN 1024
#define PADW 132   // padded LDS row stride (words): 132%32=4 -> uniform banks for
                   // lane-consecutive row access; 132%4==0 -> float4 aligned

// Math:
//   t[bn,o]  = sum_h nf[bn,h]*Wt[o,h] + bt[o]
//   g[bn,e'] : e'=0..31  -> sum_o t[bn,o]*W1[e, o]    + b1[e]   (i-half)
//              e'=32..63 -> sum_o t[bn,o]*W1[e, 128+o]          (j-half)
//   ew(n,m)  = b2 + sum_e relu(g[n,e] + g[m,32+e]) * W2[e]
//   out      = sigmoid(ew) * adj[n,m]   (exactly 0 where adj==0 -> skip)
// ws layout (floats): gall[2048*64]

__device__ __forceinline__ float hsum4(float4 a) {
    return (a.x + a.y) + (a.z + a.w);
}

// k1: 256 blocks x 256 threads, 8 nodes/block. Weights staged in LDS (coalesced
// global loads), then conflict-free register-tiled dots.  (unchanged from R4)
__global__ __launch_bounds__(256) void gall_kernel(
    const float* __restrict__ nf, const float* __restrict__ Wt,
    const float* __restrict__ bt, const float* __restrict__ W1,
    const float* __restrict__ b1, float* __restrict__ gall)
{
    __shared__ float s_Wt[128 * PADW];  // Wt[o][h]
    __shared__ float s_W1[64 * PADW];   // W1'[ep][o], ep = half*32+e
    __shared__ float s_nf[8 * 128];
    __shared__ float s_t[8 * PADW];

    const int tid = threadIdx.x;
    const int nb  = blockIdx.x * 8;

    for (int idx = tid; idx < 128 * 128; idx += 256)
        s_Wt[(idx >> 7) * PADW + (idx & 127)] = Wt[idx];
    for (int idx = tid; idx < 32 * 256; idx += 256) {
        const int e = idx >> 8, j = idx & 255;
        const int half = j >> 7, o = j & 127;
        s_W1[(half * 32 + e) * PADW + o] = W1[idx];
    }
    for (int idx = tid; idx < 8 * 128; idx += 256)
        s_nf[idx] = nf[nb * 128 + idx];
    __syncthreads();

    // t-step: t[8][128]. thread: o = tid&127 (lane-consecutive -> uniform banks),
    // node group n0 = (tid>>7)*4. 1 Wt stream-read per 16 FMA.
    {
        const int o  = tid & 127;
        const int n0 = (tid >> 7) * 4;
        const float* wrow = s_Wt + o * PADW;
        float4 A0 = {0,0,0,0}, A1 = {0,0,0,0}, A2 = {0,0,0,0}, A3 = {0,0,0,0};
        #pragma unroll 8
        for (int hc = 0; hc < 32; ++hc) {
            const float4 w  = *reinterpret_cast<const float4*>(wrow + 4 * hc);
            const float4 x0 = *reinterpret_cast<const float4*>(s_nf + (n0 + 0) * 128 + 4 * hc);
            const float4 x1 = *reinterpret_cast<const float4*>(s_nf + (n0 + 1) * 128 + 4 * hc);
            const float4 x2 = *reinterpret_cast<const float4*>(s_nf + (n0 + 2) * 128 + 4 * hc);
            const float4 x3 = *reinterpret_cast<const float4*>(s_nf + (n0 + 3) * 128 + 4 * hc);
            A0.x = fmaf(w.x, x0.x, A0.x); A0.y = fmaf(w.y, x0.y, A0.y);
            A0.z = fmaf(w.z, x0.z, A0.z); A0.w = fmaf(w.w, x0.w, A0.w);
            A1.x = fmaf(w.x, x1.x, A1.x); A1.y = fmaf(w.y, x1.y, A1.y);
            A1.z = fmaf(w.z, x1.z, A1.z); A1.w = fmaf(w.w, x1.w, A1.w);
            A2.x = fmaf(w.x, x2.x, A2.x); A2.y = fmaf(w.y, x2.y, A2.y);
            A2.z = fmaf(w.z, x2.z, A2.z); A2.w = fmaf(w.w, x2.w, A2.w);
            A3.x = fmaf(w.x, x3.x, A3.x); A3.y = fmaf(w.y, x3.y, A3.y);
            A3.z = fmaf(w.z, x3.z, A3.z); A3.w = fmaf(w.w, x3.w, A3.w);
        }
        const float btv = bt[o];
        s_t[(n0 + 0) * PADW + o] = hsum4(A0) + btv;
        s_t[(n0 + 1) * PADW + o] = hsum4(A1) + btv;
        s_t[(n0 + 2) * PADW + o] = hsum4(A2) + btv;
        s_t[(n0 + 3) * PADW + o] = hsum4(A3) + btv;
    }
    __syncthreads();

    // g-step: g[8][64]. thread: ep = tid&63 (uniform banks), nodes n0 = (tid>>6)*2.
    {
        const int ep = tid & 63;
        const int n0 = (tid >> 6) * 2;
        const int e = ep & 31, half = ep >> 5;
        const float* w1row = s_W1 + ep * PADW;
        const float* t0 = s_t + (n0 + 0) * PADW;
        const float* t1 = s_t + (n0 + 1) * PADW;
        float4 A0 = {0,0,0,0}, A1 = {0,0,0,0};
        #pragma unroll 8
        for (int oc = 0; oc < 32; ++oc) {
            const float4 w  = *reinterpret_cast<const float4*>(w1row + 4 * oc);
            const float4 x0 = *reinterpret_cast<const float4*>(t0 + 4 * oc);
            const float4 x1 = *reinterpret_cast<const float4*>(t1 + 4 * oc);
            A0.x = fmaf(w.x, x0.x, A0.x); A0.y = fmaf(w.y, x0.y, A0.y);
            A0.z = fmaf(w.z, x0.z, A0.z); A0.w = fmaf(w.w, x0.w, A0.w);
            A1.x = fmaf(w.x, x1.x, A1.x); A1.y = fmaf(w.y, x1.y, A1.y);
            A1.z = fmaf(w.z, x1.z, A1.z); A1.w = fmaf(w.w, x1.w, A1.w);
        }
        float g0 = hsum4(A0), g1 = hsum4(A1);
        if (half == 0) { const float bv = b1[e]; g0 += bv; g1 += bv; }
        gall[(nb + n0 + 0) * 64 + ep] = g0;   // lanes ep-consecutive -> coalesced
        gall[(nb + n0 + 1) * 64 + ep] = g1;
    }
}

// k2: one block per row n, BOTH batches (adj row shared; active-m list shared).
// Wave-ballot compaction: 1 LDS atomic per wave per cc (16/block), dense lanes
// on the ~5% active edges, dense float4 stores. Values keyed by entry index ->
// output deterministic regardless of wave ordering.
__global__ __launch_bounds__(256) void edge_kernel(
    const float* __restrict__ adj, const float* __restrict__ gall,
    const float* __restrict__ W2, const float* __restrict__ b2,
    float* __restrict__ out)
{
    const int n    = blockIdx.x;
    const int tid  = threadIdx.x;
    const int lane = tid & 63;

    __shared__ float s_u[2][32];
    __shared__ float s_w2[32];
    __shared__ unsigned s_cnt;
    __shared__ unsigned short s_ent[NN];   // active m list (shared by both b)
    __shared__ float s_res[2 * NN];        // sigmoid results: [p]=b0, [cnt+p]=b1

    const int m0 = tid * 4;
    const float4 a4 = *reinterpret_cast<const float4*>(adj + n * NN + m0);

    if (tid < 32)       s_u[0][tid]      = gall[n * 64 + tid];
    else if (tid < 64)  s_u[1][tid & 31] = gall[(NN + n) * 64 + (tid & 31)];
    else if (tid < 96)  s_w2[tid & 31]   = W2[tid & 31];
    if (tid == 0) s_cnt = 0;
    __syncthreads();

    const float* ap = &a4.x;
    const unsigned long long below = (1ULL << lane) - 1ULL;
    int pidx[4];

    #pragma unroll
    for (int cc = 0; cc < 4; ++cc) {
        const bool act = (ap[cc] != 0.f);
        const unsigned long long mask = __ballot(act);
        int base = 0;
        if (lane == 0)
            base = (int)atomicAdd(&s_cnt, (unsigned)__popcll(mask));
        base = __shfl(base, 0, 64);
        pidx[cc] = -1;
        if (act) {
            const int p = base + __popcll(mask & below);
            s_ent[p] = (unsigned short)(m0 + cc);
            pidx[cc] = p;
        }
    }
    __syncthreads();
    const int cnt = (int)s_cnt;
    const float b2v = b2[0];

    for (int w = tid; w < 2 * cnt; w += 256) {
        const int bb = (w >= cnt);
        const int m  = s_ent[w - bb * cnt];
        const float* gj = gall + (bb * NN + m) * 64 + 32;  // contiguous 128B gather
        const float* uu = s_u[bb];
        float ew = b2v;
        #pragma unroll
        for (int j = 0; j < 8; ++j) {
            const float4 gv = *reinterpret_cast<const float4*>(gj + 4 * j);
            ew = fmaf(fmaxf(uu[4 * j + 0] + gv.x, 0.f), s_w2[4 * j + 0], ew);
            ew = fmaf(fmaxf(uu[4 * j + 1] + gv.y, 0.f), s_w2[4 * j + 1], ew);
            ew = fmaf(fmaxf(uu[4 * j + 2] + gv.z, 0.f), s_w2[4 * j + 2], ew);
            ew = fmaf(fmaxf(uu[4 * j + 3] + gv.w, 0.f), s_w2[4 * j + 3], ew);
        }
        s_res[w] = 1.f / (1.f + __expf(-ew));
    }
    __syncthreads();

    float4 r0, r1;
    float* rp0 = &r0.x;
    float* rp1 = &r1.x;
    #pragma unroll
    for (int cc = 0; cc < 4; ++cc) {
        if (pidx[cc] >= 0) {
            rp0[cc] = ap[cc] * s_res[pidx[cc]];
            rp1[cc] = ap[cc] * s_res[cnt + pidx[cc]];
        } else {
            rp0[cc] = 0.f;
            rp1[cc] = 0.f;
        }
    }
    *reinterpret_cast<float4*>(out + (size_t)n * NN + m0) = r0;
    *reinterpret_cast<float4*>(out + (size_t)(NN + n) * NN + m0) = r1;
}

extern "C" void kernel_launch(void* const* d_in, const int* in_sizes, int n_in,
                              void* d_out, int out_size, void* d_ws, size_t ws_size,
                              hipStream_t stream)
{
    const float* nf  = (const float*)d_in[0];
    const float* adj = (const float*)d_in[1];
    const float* Wt  = (const float*)d_in[2];
    const float* bt  = (const float*)d_in[3];
    const float* W1  = (const float*)d_in[4];
    const float* b1  = (const float*)d_in[5];
    const float* W2  = (const float*)d_in[6];
    const float* b2  = (const float*)d_in[7];
    float* out  = (float*)d_out;
    float* gall = (float*)d_ws;   // 2048*64 floats

    hipLaunchKernelGGL(gall_kernel, dim3(256), dim3(256), 0, stream,
                       nf, Wt, bt, W1, b1, gall);
    hipLaunchKernelGGL(edge_kernel, dim3(NN), dim3(256), 0, stream,
                       adj, gall, W2, b2, out);
}